// Round 6
// baseline (2651.619 us; speedup 1.0000x reference)
//
#include <hip/hip_runtime.h>
#include <math.h>

#define H 128
#define H4 (H/4)
#define KK 12
#define MSUB 4
#define FF 120000
#define SS 10000
#define NN 2500
#define NBATCH 50
#define NLAYER 4
#define EINTRA 240000
#define EINTER 40000
#define HH (H*H)
#define BN_EPS 1e-5f
#define CAP_I 24
#define CAP_E 96
#define WFRAG_SHORTS 32768   // [2][4][8][64][8] shorts = 64 KB per matrix

typedef short short8 __attribute__((ext_vector_type(8)));
typedef float floatx4 __attribute__((ext_vector_type(4)));

__device__ __forceinline__ unsigned short f2bf_rne(float x){
  unsigned u = __float_as_uint(x);
  unsigned r = u + 0x7FFFu + ((u >> 16) & 1u);
  return (unsigned short)(r >> 16);
}

// ---------------- small helpers ----------------

__global__ void k_zero(float* __restrict__ p, int n){
  int i = blockIdx.x*256 + threadIdx.x;
  if (i < n) p[i] = 0.f;
}

__global__ void k_zeroi(int* __restrict__ p, int n){
  int i = blockIdx.x*256 + threadIdx.x;
  if (i < n) p[i] = 0;
}

// ---------------- W pre-split: frag-major bf16 hi/lo, col = (lane&15)*8 + nt ----------------

__global__ void k_wprep(const float* __restrict__ W1, const float* __restrict__ W2,
                        const float* __restrict__ SW, const float* __restrict__ RW,
                        const float* __restrict__ IW1, const float* __restrict__ IW2,
                        short* __restrict__ wf){
  int m = blockIdx.y;
  int layer = m / 6, kind = m % 6;
  const float* Wsrc = (kind==0 ? W1 : kind==1 ? W2 : kind==2 ? SW :
                       kind==3 ? RW : kind==4 ? IW1 : IW2) + (size_t)layer*HH;
  int slot = blockIdx.x*256 + threadIdx.x;   // 0..4095
  int s  = slot >> 11;
  int ks = (slot >> 9) & 3;
  int nt = (slot >> 6) & 7;
  int l  = slot & 63;
  int quad = l >> 4, n15 = l & 15;
  int col = n15*8 + nt;
  short v8[8];
  #pragma unroll
  for (int j = 0; j < 8; ++j){
    int k = ks*32 + quad*8 + j;
    float v = Wsrc[(size_t)k*H + col];
    unsigned short hb = f2bf_rne(v);
    if (s == 0) v8[j] = (short)hb;
    else {
      float hf = __uint_as_float((unsigned)hb << 16);
      v8[j] = (short)f2bf_rne(v - hf);
    }
  }
  *(short8*)(wf + (size_t)m*WFRAG_SHORTS + (size_t)slot*8) = *(const short8*)v8;
}

// ---------------- CSR bucket build: packed (edge, src) ----------------

__global__ void k_bucket2(const int* __restrict__ dst, const int* __restrict__ src,
                          int E, int* __restrict__ cnt, int2* __restrict__ beid, int cap){
  int e = blockIdx.x*256 + threadIdx.x;
  if (e >= E) return;
  int d = dst[e];
  int p = atomicAdd(&cnt[d], 1);
  if (p < cap) beid[(size_t)d*cap + p] = make_int2(e, src[e]);
}

// ---------------- input encoding ----------------

__global__ void k_encode(float* __restrict__ h, const int* __restrict__ xtok,
                         const int* __restrict__ dist, const int* __restrict__ nids,
                         const int* __restrict__ subb, const float* __restrict__ lp,
                         const float* __restrict__ aemb, const float* __restrict__ demb,
                         const float* __restrict__ lw, const float* __restrict__ lb){
  int idx = blockIdx.x*256 + threadIdx.x;
  if (idx >= FF*H4) return;
  int f = idx >> 5; int c = (idx & 31) << 2;
  float vf = (nids[f] >= 0) ? 1.f : 0.f;
  float l = lp[subb[f]];
  float4 a = *(const float4*)(aemb + (size_t)xtok[f]*H + c);
  float4 d = *(const float4*)(demb + (size_t)dist[f]*H + c);
  float4 w = *(const float4*)(lw + c);
  float4 b = *(const float4*)(lb + c);
  float4 o;
  o.x = (a.x + d.x + fmaxf(fmaf(l, w.x, b.x), 0.f)) * vf;
  o.y = (a.y + d.y + fmaxf(fmaf(l, w.y, b.y), 0.f)) * vf;
  o.z = (a.z + d.z + fmaxf(fmaf(l, w.z, b.z), 0.f)) * vf;
  o.w = (a.w + d.w + fmaxf(fmaf(l, w.w, b.w), 0.f)) * vf;
  *(float4*)(h + (size_t)f*H + c) = o;
}

// ---------------- HT weights (rid = s//M by construction) ----------------

__global__ void k_htw(const int* __restrict__ nids, const int* __restrict__ rfi,
                      const float* __restrict__ lp, const float* __restrict__ alpha,
                      float* __restrict__ htw){
  int n = blockIdx.x*256 + threadIdx.x;
  if (n >= NN) return;
  float a = alpha[0];
  float w[MSUB]; float sum = 0.f;
  #pragma unroll
  for (int m = 0; m < MSUB; ++m){
    int s = n*MSUB + m;
    int rid = nids[rfi[s]];
    float wm = (rid >= 0) ? expf(-a*lp[s]) : 0.f;
    w[m] = wm; sum += wm;
  }
  float inv = 1.f / (sum + 1e-16f);
  #pragma unroll
  for (int m = 0; m < MSUB; ++m) htw[n*MSUB + m] = w[m]*inv;
}

// ---------------- GINE gather: out[f] = x[f] + sum relu(x[src]+ea) ----------------

__global__ void k_gine_gather(float* __restrict__ outa, const float* __restrict__ x,
                              const float* __restrict__ ea, const int* __restrict__ cnt,
                              const int2* __restrict__ beid, int rows, int cap){
  int idx = blockIdx.x*256 + threadIdx.x;
  if (idx >= rows*H4) return;
  int f = idx >> 5; int c = (idx & 31) << 2;
  float4 acc = *(const float4*)(x + (size_t)f*H + c);
  int n = cnt[f]; if (n > cap) n = cap;
  const int2* bl = beid + (size_t)f*cap;
  for (int i = 0; i < n; ++i){
    int2 es = bl[i];
    float4 xv = *(const float4*)(x + (size_t)es.y*H + c);
    float4 ev = *(const float4*)(ea + (size_t)es.x*H + c);
    acc.x += fmaxf(xv.x + ev.x, 0.f);
    acc.y += fmaxf(xv.y + ev.y, 0.f);
    acc.z += fmaxf(xv.z + ev.z, 0.f);
    acc.w += fmaxf(xv.w + ev.w, 0.f);
  }
  *(float4*)(outa + (size_t)f*H + c) = acc;
}

// ---------------- HT root gather to canonical nodes ----------------

__global__ void k_canon(float* __restrict__ canon, const float* __restrict__ h,
                        const float* __restrict__ htw, const int* __restrict__ rfi){
  int idx = blockIdx.x*256 + threadIdx.x;
  if (idx >= NN*H4) return;
  int n = idx >> 5; int c = (idx & 31) << 2;
  float4 acc = make_float4(0.f,0.f,0.f,0.f);
  #pragma unroll
  for (int m = 0; m < MSUB; ++m){
    int s = n*MSUB + m;
    float w = htw[s];
    const float* p = h + (size_t)rfi[s]*H + c;
    acc.x += w*p[0]; acc.y += w*p[1]; acc.z += w*p[2]; acc.w += w*p[3];
  }
  *(float4*)(canon + (size_t)n*H + c) = acc;
}

// ---------------- split-bf16 MFMA matmul, depth-1 A prefetch ----------------
// mode 0: out = in@W + bias;  mode 1: + relu
// mode 2: fused combine (FF only, rows % 64 == 0): r1 = in@W+bias; h1 = bn(hmid)*vf;
//         root: o = h1 + hinter[nid]*vf; else o = h1 + r1 + r2[r/12]; out = relu(o)*vf

__global__ __launch_bounds__(256, 2) void k_mm_mfma(
    const float* __restrict__ in, float* __restrict__ out, int rows,
    const short* __restrict__ wf, const float* __restrict__ bias,
    int mode, const int* __restrict__ gather,
    const float* __restrict__ hmid, const float* __restrict__ r2,
    const float* __restrict__ hinter, const float* __restrict__ muinv,
    const float* __restrict__ bg, const float* __restrict__ bb,
    const int* __restrict__ nids)
{
  int ngroups = (rows + 63) >> 6;
  if ((int)blockIdx.x >= ngroups) return;

  __shared__ __align__(16) short wfrag[WFRAG_SHORTS];
  int tid = threadIdx.x;
  {
    const float4* s4 = (const float4*)wf;
    float4* d4 = (float4*)wfrag;
    #pragma unroll
    for (int i = 0; i < 16; ++i) d4[tid + i*256] = s4[tid + i*256];
  }
  __syncthreads();

  int w = tid >> 6, l = tid & 63;
  int quad = l >> 4, n15 = l & 15;
  int col0 = n15 * 8;

  float4 bv0 = *(const float4*)(bias + col0);
  float4 bv1 = *(const float4*)(bias + col0 + 4);
  float4 mu0, mu1, iv0, iv1, gg0, gg1, be0, be1;
  if (mode == 2){
    mu0 = *(const float4*)(muinv + col0);      mu1 = *(const float4*)(muinv + col0 + 4);
    iv0 = *(const float4*)(muinv + H + col0);  iv1 = *(const float4*)(muinv + H + col0 + 4);
    gg0 = *(const float4*)(bg + col0);         gg1 = *(const float4*)(bg + col0 + 4);
    be0 = *(const float4*)(bb + col0);         be1 = *(const float4*)(bb + col0 + 4);
  }

  float4 aC[8], aN[8];
  auto loadA = [&](int gg, float4* buf){
    int rload = gg*64 + w*16 + n15;
    bool ok = rload < rows;
    int ir = ok ? (gather ? gather[rload] : rload) : 0;
    const float* ap = in + (size_t)ir*H + quad*8;
    #pragma unroll
    for (int ks = 0; ks < 4; ++ks){
      buf[2*ks]   = ok ? *(const float4*)(ap + ks*32)     : make_float4(0.f,0.f,0.f,0.f);
      buf[2*ks+1] = ok ? *(const float4*)(ap + ks*32 + 4) : make_float4(0.f,0.f,0.f,0.f);
    }
  };

  loadA(blockIdx.x, aC);

  for (int g = blockIdx.x; g < ngroups; g += gridDim.x){
    int gn = g + gridDim.x;
    if (gn < ngroups) loadA(gn, aN);        // prefetch next group's A

    int rbase = g*64 + w*16 + quad*4;

    // mode 2: early-issue current group's hmid stream (rides behind the MFMAs)
    float4 hmv[8];
    if (mode == 2){
      #pragma unroll
      for (int reg = 0; reg < 4; ++reg){
        const float* hp = hmid + (size_t)(rbase + reg)*H + col0;
        hmv[2*reg]   = *(const float4*)hp;
        hmv[2*reg+1] = *(const float4*)(hp + 4);
      }
    }

    // split A -> bf16 hi/lo frags
    short8 ah[4], al[4];
    #pragma unroll
    for (int ks = 0; ks < 4; ++ks){
      float av[8] = {aC[2*ks].x, aC[2*ks].y, aC[2*ks].z, aC[2*ks].w,
                     aC[2*ks+1].x, aC[2*ks+1].y, aC[2*ks+1].z, aC[2*ks+1].w};
      #pragma unroll
      for (int j = 0; j < 8; ++j){
        unsigned short hb = f2bf_rne(av[j]);
        float hf = __uint_as_float((unsigned)hb << 16);
        ah[ks][j] = (short)hb;
        al[ks][j] = (short)f2bf_rne(av[j] - hf);
      }
    }

    floatx4 acc[8] = {};
    #pragma unroll
    for (int ks = 0; ks < 4; ++ks){
      #pragma unroll
      for (int nt = 0; nt < 8; ++nt){
        short8 bh = *(const short8*)&wfrag[((ks*8 + nt)*64 + l)*8];
        short8 bl = *(const short8*)&wfrag[(((4 + ks)*8 + nt)*64 + l)*8];
        acc[nt] = __builtin_amdgcn_mfma_f32_16x16x32_bf16(ah[ks], bh, acc[nt], 0, 0, 0);
        acc[nt] = __builtin_amdgcn_mfma_f32_16x16x32_bf16(al[ks], bh, acc[nt], 0, 0, 0);
        acc[nt] = __builtin_amdgcn_mfma_f32_16x16x32_bf16(ah[ks], bl, acc[nt], 0, 0, 0);
      }
    }

    if (mode != 2){
      #pragma unroll
      for (int reg = 0; reg < 4; ++reg){
        int r = rbase + reg;
        if (r < rows){
          float4 o0, o1;
          o0.x = acc[0][reg] + bv0.x; o0.y = acc[1][reg] + bv0.y;
          o0.z = acc[2][reg] + bv0.z; o0.w = acc[3][reg] + bv0.w;
          o1.x = acc[4][reg] + bv1.x; o1.y = acc[5][reg] + bv1.y;
          o1.z = acc[6][reg] + bv1.z; o1.w = acc[7][reg] + bv1.w;
          if (mode == 1){
            o0.x=fmaxf(o0.x,0.f); o0.y=fmaxf(o0.y,0.f); o0.z=fmaxf(o0.z,0.f); o0.w=fmaxf(o0.w,0.f);
            o1.x=fmaxf(o1.x,0.f); o1.y=fmaxf(o1.y,0.f); o1.z=fmaxf(o1.z,0.f); o1.w=fmaxf(o1.w,0.f);
          }
          *(float4*)(out + (size_t)r*H + col0)     = o0;
          *(float4*)(out + (size_t)r*H + col0 + 4) = o1;
        }
      }
    } else {
      #pragma unroll
      for (int reg = 0; reg < 4; ++reg){
        int r = rbase + reg;             // FF % 64 == 0: always in range
        int nid = nids[r];
        float vf = (nid >= 0) ? 1.f : 0.f;
        int cid = (nid < 0) ? 0 : nid;
        float4 x0 = hmv[2*reg], x1 = hmv[2*reg+1];
        float4 h10, h11;
        h10.x = ((x0.x-mu0.x)*iv0.x*gg0.x + be0.x)*vf;
        h10.y = ((x0.y-mu0.y)*iv0.y*gg0.y + be0.y)*vf;
        h10.z = ((x0.z-mu0.z)*iv0.z*gg0.z + be0.z)*vf;
        h10.w = ((x0.w-mu0.w)*iv0.w*gg0.w + be0.w)*vf;
        h11.x = ((x1.x-mu1.x)*iv1.x*gg1.x + be1.x)*vf;
        h11.y = ((x1.y-mu1.y)*iv1.y*gg1.y + be1.y)*vf;
        h11.z = ((x1.z-mu1.z)*iv1.z*gg1.z + be1.z)*vf;
        h11.w = ((x1.w-mu1.w)*iv1.w*gg1.w + be1.w)*vf;
        float4 o0, o1;
        if (r % KK == 0){
          const float* hp = hinter + (size_t)cid*H + col0;
          float4 q0 = *(const float4*)hp;
          float4 q1 = *(const float4*)(hp + 4);
          o0.x = h10.x + q0.x*vf; o0.y = h10.y + q0.y*vf;
          o0.z = h10.z + q0.z*vf; o0.w = h10.w + q0.w*vf;
          o1.x = h11.x + q1.x*vf; o1.y = h11.y + q1.y*vf;
          o1.z = h11.z + q1.z*vf; o1.w = h11.w + q1.w*vf;
        } else {
          const float* rp = r2 + (size_t)(r/KK)*H + col0;
          float4 q0 = *(const float4*)rp;
          float4 q1 = *(const float4*)(rp + 4);
          o0.x = h10.x + (acc[0][reg]+bv0.x) + q0.x;
          o0.y = h10.y + (acc[1][reg]+bv0.y) + q0.y;
          o0.z = h10.z + (acc[2][reg]+bv0.z) + q0.z;
          o0.w = h10.w + (acc[3][reg]+bv0.w) + q0.w;
          o1.x = h11.x + (acc[4][reg]+bv1.x) + q1.x;
          o1.y = h11.y + (acc[5][reg]+bv1.y) + q1.y;
          o1.z = h11.z + (acc[6][reg]+bv1.z) + q1.z;
          o1.w = h11.w + (acc[7][reg]+bv1.w) + q1.w;
        }
        o0.x = fmaxf(o0.x,0.f)*vf; o0.y = fmaxf(o0.y,0.f)*vf;
        o0.z = fmaxf(o0.z,0.f)*vf; o0.w = fmaxf(o0.w,0.f)*vf;
        o1.x = fmaxf(o1.x,0.f)*vf; o1.y = fmaxf(o1.y,0.f)*vf;
        o1.z = fmaxf(o1.z,0.f)*vf; o1.w = fmaxf(o1.w,0.f)*vf;
        *(float4*)(out + (size_t)r*H + col0)     = o0;
        *(float4*)(out + (size_t)r*H + col0 + 4) = o1;
      }
    }

    #pragma unroll
    for (int i = 0; i < 8; ++i) aC[i] = aN[i];
  }
}

// ---------------- BatchNorm ----------------

__global__ void k_bnstats(const float* __restrict__ x, int rows, double* __restrict__ stats){
  int g = blockIdx.x*256 + threadIdx.x;
  int c = g & (H-1);
  int rstart = g >> 7;
  int rstride = (gridDim.x*256) >> 7;
  double s = 0.0, s2 = 0.0;
  for (int r = rstart; r < rows; r += rstride){
    float v = x[(size_t)r*H + c];
    s += v; s2 += (double)v*(double)v;
  }
  atomicAdd(&stats[c], s);
  atomicAdd(&stats[H+c], s2);
}

__global__ void k_bnfin(double* __restrict__ stats, int rows, float* __restrict__ muinv){
  int c = threadIdx.x;
  if (c < H){
    double mu = stats[c] / (double)rows;
    double var = stats[H+c] / (double)rows - mu*mu;
    muinv[c]   = (float)mu;
    muinv[H+c] = (float)(1.0 / sqrt(var + (double)BN_EPS));
    stats[c] = 0.0; stats[H+c] = 0.0;
  }
}

__global__ void k_bnapply(float* __restrict__ x, const float* __restrict__ muinv,
                          const float* __restrict__ g, const float* __restrict__ b, int rows){
  int idx = blockIdx.x*256 + threadIdx.x;
  if (idx >= rows*H4) return;
  int r = idx >> 5; int c = (idx & 31) << 2;
  float4 v  = *(const float4*)(x + (size_t)r*H + c);
  float4 mu = *(const float4*)(muinv + c);
  float4 iv = *(const float4*)(muinv + H + c);
  float4 gg = *(const float4*)(g + c);
  float4 bb = *(const float4*)(b + c);
  v.x = (v.x-mu.x)*iv.x*gg.x + bb.x;
  v.y = (v.y-mu.y)*iv.y*gg.y + bb.y;
  v.z = (v.z-mu.z)*iv.z*gg.z + bb.z;
  v.w = (v.w-mu.w)*iv.w*gg.w + bb.w;
  *(float4*)(x + (size_t)r*H + c) = v;
}

// ---------------- readout ----------------

__global__ void k_hsub(float* __restrict__ hsub, const float* __restrict__ h){
  int idx = blockIdx.x*256 + threadIdx.x;
  if (idx >= SS*H4) return;
  int s = idx >> 5; int c = (idx & 31) << 2;
  float4 acc = make_float4(0.f,0.f,0.f,0.f);
  const float* base = h + (size_t)s*KK*H + c;
  #pragma unroll
  for (int k = 0; k < KK; ++k){
    float4 v = *(const float4*)(base + (size_t)k*H);
    acc.x += v.x; acc.y += v.y; acc.z += v.z; acc.w += v.w;
  }
  *(float4*)(hsub + (size_t)s*H + c) = acc;
}

__global__ void k_poolw(float* __restrict__ poolw, const float* __restrict__ lp,
                        const float* __restrict__ alpha){
  int n = blockIdx.x*256 + threadIdx.x;
  if (n >= NN) return;
  float a = alpha[0];
  float s0 = -a*lp[n*MSUB+0], s1 = -a*lp[n*MSUB+1], s2 = -a*lp[n*MSUB+2], s3 = -a*lp[n*MSUB+3];
  float m = fmaxf(fmaxf(s0,s1), fmaxf(s2,s3));
  float e0 = expf(s0-m), e1 = expf(s1-m), e2 = expf(s2-m), e3 = expf(s3-m);
  float sum = e0+e1+e2+e3;
  poolw[n*MSUB+0] = e0/sum; poolw[n*MSUB+1] = e1/sum;
  poolw[n*MSUB+2] = e2/sum; poolw[n*MSUB+3] = e3/sum;
}

__global__ void k_nodeemb(float* __restrict__ nemb, const float* __restrict__ hsub,
                          const float* __restrict__ poolw){
  int idx = blockIdx.x*256 + threadIdx.x;
  if (idx >= NN*H4) return;
  int n = idx >> 5; int c = (idx & 31) << 2;
  float w0 = poolw[n*MSUB+0], w1 = poolw[n*MSUB+1], w2 = poolw[n*MSUB+2], w3 = poolw[n*MSUB+3];
  const float* base = hsub + (size_t)n*MSUB*H + c;
  float4 v0 = *(const float4*)(base + 0*H);
  float4 v1 = *(const float4*)(base + 1*H);
  float4 v2 = *(const float4*)(base + 2*H);
  float4 v3 = *(const float4*)(base + 3*H);
  float4 o;
  o.x = w0*v0.x + w1*v1.x + w2*v2.x + w3*v3.x;
  o.y = w0*v0.y + w1*v1.y + w2*v2.y + w3*v3.y;
  o.z = w0*v0.z + w1*v1.z + w2*v2.z + w3*v3.z;
  o.w = w0*v0.w + w1*v1.w + w2*v2.w + w3*v3.w;
  *(float4*)(nemb + (size_t)n*H + c) = o;
}

__global__ void k_out(float* __restrict__ out, const float* __restrict__ nemb,
                      const float* __restrict__ muinv, const float* __restrict__ g,
                      const float* __restrict__ b){
  int idx = blockIdx.x*256 + threadIdx.x;
  if (idx >= NBATCH*H) return;
  int bi = idx >> 7; int c = idx & (H-1);
  float mu = muinv[c], iv = muinv[H+c], gg = g[c], bb = b[c];
  float acc = 0.f;
  const float* base = nemb + (size_t)bi*(NN/NBATCH)*H + c;
  for (int i = 0; i < NN/NBATCH; ++i)
    acc += (base[(size_t)i*H] - mu)*iv*gg + bb;
  out[idx] = acc;
}

// ---------------- launch ----------------

extern "C" void kernel_launch(void* const* d_in, const int* in_sizes, int n_in,
                              void* d_out, int out_size, void* d_ws, size_t ws_size,
                              hipStream_t stream) {
  const int*   x_tok      = (const int*)  d_in[0];
  const int*   dist       = (const int*)  d_in[1];
  const int*   node_ids   = (const int*)  d_in[2];
  const int*   sub_batch  = (const int*)  d_in[4];
  const int*   rfi        = (const int*)  d_in[5];
  const int*   intra_ei   = (const int*)  d_in[6];
  const int*   edge_index = (const int*)  d_in[7];
  const float* lp         = (const float*)d_in[9];
  const float* ea_flat    = (const float*)d_in[10];
  const float* edge_attr  = (const float*)d_in[11];
  const float* atom_emb   = (const float*)d_in[12];
  const float* dist_emb   = (const float*)d_in[13];
  const float* logp_w     = (const float*)d_in[14];
  const float* logp_b     = (const float*)d_in[15];
  const float* intra_W1   = (const float*)d_in[16];
  const float* intra_b1   = (const float*)d_in[17];
  const float* intra_W2   = (const float*)d_in[18];
  const float* intra_b2   = (const float*)d_in[19];
  const float* intra_bn_g = (const float*)d_in[20];
  const float* intra_bn_b = (const float*)d_in[21];
  const float* self_W     = (const float*)d_in[22];
  const float* self_b     = (const float*)d_in[23];
  const float* root_W     = (const float*)d_in[24];
  const float* root_b     = (const float*)d_in[25];
  const float* inter_W1   = (const float*)d_in[26];
  const float* inter_b1   = (const float*)d_in[27];
  const float* inter_W2   = (const float*)d_in[28];
  const float* inter_b2   = (const float*)d_in[29];
  const float* inter_bn_g = (const float*)d_in[30];
  const float* inter_bn_b = (const float*)d_in[31];
  const float* ro_bn_g    = (const float*)d_in[32];
  const float* ro_bn_b    = (const float*)d_in[33];
  const float* alpha_pool = (const float*)d_in[34];
  const float* alpha_inter= (const float*)d_in[35];

  const int* isrc = intra_ei;
  const int* idst = intra_ei + EINTRA;
  const int* esrc = edge_index;
  const int* edst = edge_index + EINTER;

  float* out = (float*)d_out;

  char* ws = (char*)d_ws;
  size_t off = 0;
  auto nxt = [&](size_t bytes) -> void* {
    void* p = ws + off;
    off += (bytes + 255) & ~(size_t)255;
    return p;
  };
  float*  P0     = (float*) nxt((size_t)FF*H*4);
  float*  P1     = (float*) nxt((size_t)FF*H*4);
  float*  P2     = (float*) nxt((size_t)FF*H*4);
  float*  r2     = (float*) nxt((size_t)SS*H*4);
  float*  canon  = (float*) nxt((size_t)NN*H*4);
  float*  agg2   = (float*) nxt((size_t)NN*H*4);
  float*  hsub   = (float*) nxt((size_t)SS*H*4);
  float*  nemb   = (float*) nxt((size_t)NN*H*4);
  float*  htw    = (float*) nxt((size_t)SS*4);
  float*  poolw  = (float*) nxt((size_t)NN*MSUB*4);
  double* statsA = (double*)nxt((size_t)2*H*8);
  double* statsB = (double*)nxt((size_t)2*H*8);
  float*  muinvA = (float*) nxt((size_t)2*H*4);
  float*  muinvB = (float*) nxt((size_t)2*H*4);
  short*  wsplit = (short*) nxt((size_t)24*WFRAG_SHORTS*2);
  int*    icnt   = (int*)   nxt((size_t)FF*4);
  int2*   ibeid  = (int2*)  nxt((size_t)FF*CAP_I*8);
  int*    ecnt   = (int*)   nxt((size_t)NN*4);
  int2*   ebeid  = (int2*)  nxt((size_t)NN*CAP_E*8);
  (void)ws_size; (void)n_in; (void)in_sizes; (void)out_size; (void)sub_batch;

  const int G_FH4 = FF*H4/256;
  const int G_SH4 = SS*H4/256;
  const int G_NH4 = (NN*H4 + 255)/256;
  const int G_N   = (NN + 255)/256;
  const int G_MM_F = 512;
  const int G_MM_S = (SS + 63)/64;
  const int G_MM_N = (NN + 63)/64;

  k_zero<<<2, 256, 0, stream>>>((float*)statsA, 2*H*2);
  k_zero<<<2, 256, 0, stream>>>((float*)statsB, 2*H*2);
  k_zeroi<<<(FF+255)/256, 256, 0, stream>>>(icnt, FF);
  k_zeroi<<<G_N, 256, 0, stream>>>(ecnt, NN);

  k_wprep<<<dim3(16,24), 256, 0, stream>>>(intra_W1, intra_W2, self_W, root_W,
                                           inter_W1, inter_W2, wsplit);
  k_bucket2<<<(EINTRA+255)/256, 256, 0, stream>>>(idst, isrc, EINTRA, icnt, ibeid, CAP_I);
  k_bucket2<<<(EINTER+255)/256, 256, 0, stream>>>(edst, esrc, EINTER, ecnt, ebeid, CAP_E);

  k_encode<<<G_FH4, 256, 0, stream>>>(P0, x_tok, dist, node_ids, sub_batch, lp,
                                      atom_emb, dist_emb, logp_w, logp_b);
  k_htw<<<G_N, 256, 0, stream>>>(node_ids, rfi, lp, alpha_inter, htw);

  // 3-buffer rotation: X = h, per layer: gather X->Y, mm1 Y->Z, mm2 Z->Y,
  // mode2 reads (X, Y) writes Z; rotate (X,Y,Z) <- (Z,X,Y). Keeps working set in L3.
  float* X = P0; float* Y = P1; float* Z = P2;
  for (int l = 0; l < NLAYER; ++l){
    const short* wfL = wsplit + (size_t)l*6*WFRAG_SHORTS;

    k_gine_gather<<<G_FH4, 256, 0, stream>>>(Y, X, ea_flat, icnt, ibeid, FF, CAP_I);
    k_mm_mfma<<<G_MM_F, 256, 0, stream>>>(Y, Z, FF, wfL + 0*WFRAG_SHORTS,
        intra_b1 + (size_t)l*H, 1, nullptr,
        nullptr,nullptr,nullptr,nullptr,nullptr,nullptr,nullptr);
    k_mm_mfma<<<G_MM_F, 256, 0, stream>>>(Z, Y, FF, wfL + 1*WFRAG_SHORTS,
        intra_b2 + (size_t)l*H, 0, nullptr,
        nullptr,nullptr,nullptr,nullptr,nullptr,nullptr,nullptr);
    k_bnstats<<<512, 256, 0, stream>>>(Y, FF, statsA);
    k_bnfin<<<1, 128, 0, stream>>>(statsA, FF, muinvA);

    k_canon<<<G_NH4, 256, 0, stream>>>(canon, X, htw, rfi);
    k_mm_mfma<<<G_MM_S, 256, 0, stream>>>(X, r2, SS, wfL + 3*WFRAG_SHORTS,
        root_b + (size_t)l*H, 0, rfi,
        nullptr,nullptr,nullptr,nullptr,nullptr,nullptr,nullptr);

    k_gine_gather<<<G_NH4, 256, 0, stream>>>(agg2, canon, edge_attr, ecnt, ebeid, NN, CAP_E);
    k_mm_mfma<<<G_MM_N, 256, 0, stream>>>(agg2, hsub, NN, wfL + 4*WFRAG_SHORTS,
        inter_b1 + (size_t)l*H, 1, nullptr,
        nullptr,nullptr,nullptr,nullptr,nullptr,nullptr,nullptr);
    k_mm_mfma<<<G_MM_N, 256, 0, stream>>>(hsub, agg2, NN, wfL + 5*WFRAG_SHORTS,
        inter_b2 + (size_t)l*H, 0, nullptr,
        nullptr,nullptr,nullptr,nullptr,nullptr,nullptr,nullptr);
    k_bnstats<<<128, 256, 0, stream>>>(agg2, NN, statsB);
    k_bnfin<<<1, 128, 0, stream>>>(statsB, NN, muinvB);
    k_bnapply<<<G_NH4, 256, 0, stream>>>(agg2, muinvB, inter_bn_g + (size_t)l*H,
                                         inter_bn_b + (size_t)l*H, NN);

    // fused self-matmul + combine: reads X (A) and Y (h1raw), writes Z
    k_mm_mfma<<<G_MM_F, 256, 0, stream>>>(X, Z, FF, wfL + 2*WFRAG_SHORTS,
        self_b + (size_t)l*H, 2, nullptr,
        Y, r2, agg2, muinvA,
        intra_bn_g + (size_t)l*H, intra_bn_b + (size_t)l*H, node_ids);

    float* t = Z; Z = Y; Y = X; X = t;   // new h = old Z
  }

  // readout (h = X)
  k_hsub<<<G_SH4, 256, 0, stream>>>(hsub, X);
  k_poolw<<<G_N, 256, 0, stream>>>(poolw, lp, alpha_pool);
  k_nodeemb<<<G_NH4, 256, 0, stream>>>(nemb, hsub, poolw);
  k_bnstats<<<128, 256, 0, stream>>>(nemb, NN, statsB);
  k_bnfin<<<1, 128, 0, stream>>>(statsB, NN, muinvB);
  k_out<<<(NBATCH*H+255)/256, 256, 0, stream>>>(out, nemb, muinvB, ro_bn_g, ro_bn_b);
}

// Round 7
// 2260.761 us; speedup vs baseline: 1.1729x; 1.1729x over previous
//
#include <hip/hip_runtime.h>
#include <math.h>

#define H 128
#define H4 (H/4)
#define KK 12
#define MSUB 4
#define FF 120000
#define SS 10000
#define NN 2500
#define NBATCH 50
#define NLAYER 4
#define EINTRA 240000
#define EINTER 40000
#define HH (H*H)
#define BN_EPS 1e-5f
#define CAP_I 24
#define CAP_E 96
#define WFRAG_SHORTS 32768   // per matrix: 2 halves x 16384 shorts (32 KB per half)
#define HALF_SHORTS 16384

typedef short short8 __attribute__((ext_vector_type(8)));
typedef float floatx4 __attribute__((ext_vector_type(4)));

__device__ __forceinline__ unsigned short f2bf_rne(float x){
  unsigned u = __float_as_uint(x);
  unsigned r = u + 0x7FFFu + ((u >> 16) & 1u);
  return (unsigned short)(r >> 16);
}

// ---------------- small helpers ----------------

__global__ void k_zero(float* __restrict__ p, int n){
  int i = blockIdx.x*256 + threadIdx.x;
  if (i < n) p[i] = 0.f;
}

__global__ void k_zeroi(int* __restrict__ p, int n){
  int i = blockIdx.x*256 + threadIdx.x;
  if (i < n) p[i] = 0;
}

// ---------------- W pre-split: bf16 hi/lo frag-major, halved over N ----------------
// col = nt*16 + n15 (nt in [0,8)); half = nt>>2 stored contiguously (32 KB each).
// Within a half: index (((s*4+ks)*4 + nt4)*64 + l)*8 + j

__global__ void k_wprep(const float* __restrict__ W1, const float* __restrict__ W2,
                        const float* __restrict__ SW, const float* __restrict__ RW,
                        const float* __restrict__ IW1, const float* __restrict__ IW2,
                        short* __restrict__ wf){
  int m = blockIdx.y;
  int layer = m / 6, kind = m % 6;
  const float* Wsrc = (kind==0 ? W1 : kind==1 ? W2 : kind==2 ? SW :
                       kind==3 ? RW : kind==4 ? IW1 : IW2) + (size_t)layer*HH;
  int slot = blockIdx.x*256 + threadIdx.x;   // 0..4095
  int s  = slot >> 11;
  int ks = (slot >> 9) & 3;
  int nt = (slot >> 6) & 7;
  int l  = slot & 63;
  int quad = l >> 4, n15 = l & 15;
  int col = nt*16 + n15;
  short v8[8];
  #pragma unroll
  for (int j = 0; j < 8; ++j){
    int k = ks*32 + quad*8 + j;
    float v = Wsrc[(size_t)k*H + col];
    unsigned short hb = f2bf_rne(v);
    if (s == 0) v8[j] = (short)hb;
    else {
      float hf = __uint_as_float((unsigned)hb << 16);
      v8[j] = (short)f2bf_rne(v - hf);
    }
  }
  int half = nt >> 2, nt4 = nt & 3;
  size_t o = (size_t)m*WFRAG_SHORTS + (size_t)half*HALF_SHORTS
           + (size_t)((((s*4 + ks)*4 + nt4)*64 + l)*8);
  *(short8*)(wf + o) = *(const short8*)v8;
}

// ---------------- CSR bucket build: packed (edge, src) ----------------

__global__ void k_bucket2(const int* __restrict__ dst, const int* __restrict__ src,
                          int E, int* __restrict__ cnt, int2* __restrict__ beid, int cap){
  int e = blockIdx.x*256 + threadIdx.x;
  if (e >= E) return;
  int d = dst[e];
  int p = atomicAdd(&cnt[d], 1);
  if (p < cap) beid[(size_t)d*cap + p] = make_int2(e, src[e]);
}

// ---------------- input encoding ----------------

__global__ void k_encode(float* __restrict__ h, const int* __restrict__ xtok,
                         const int* __restrict__ dist, const int* __restrict__ nids,
                         const int* __restrict__ subb, const float* __restrict__ lp,
                         const float* __restrict__ aemb, const float* __restrict__ demb,
                         const float* __restrict__ lw, const float* __restrict__ lb){
  int idx = blockIdx.x*256 + threadIdx.x;
  if (idx >= FF*H4) return;
  int f = idx >> 5; int c = (idx & 31) << 2;
  float vf = (nids[f] >= 0) ? 1.f : 0.f;
  float l = lp[subb[f]];
  float4 a = *(const float4*)(aemb + (size_t)xtok[f]*H + c);
  float4 d = *(const float4*)(demb + (size_t)dist[f]*H + c);
  float4 w = *(const float4*)(lw + c);
  float4 b = *(const float4*)(lb + c);
  float4 o;
  o.x = (a.x + d.x + fmaxf(fmaf(l, w.x, b.x), 0.f)) * vf;
  o.y = (a.y + d.y + fmaxf(fmaf(l, w.y, b.y), 0.f)) * vf;
  o.z = (a.z + d.z + fmaxf(fmaf(l, w.z, b.z), 0.f)) * vf;
  o.w = (a.w + d.w + fmaxf(fmaf(l, w.w, b.w), 0.f)) * vf;
  *(float4*)(h + (size_t)f*H + c) = o;
}

// ---------------- HT weights (rid = s//M by construction) ----------------

__global__ void k_htw(const int* __restrict__ nids, const int* __restrict__ rfi,
                      const float* __restrict__ lp, const float* __restrict__ alpha,
                      float* __restrict__ htw){
  int n = blockIdx.x*256 + threadIdx.x;
  if (n >= NN) return;
  float a = alpha[0];
  float w[MSUB]; float sum = 0.f;
  #pragma unroll
  for (int m = 0; m < MSUB; ++m){
    int s = n*MSUB + m;
    int rid = nids[rfi[s]];
    float wm = (rid >= 0) ? expf(-a*lp[s]) : 0.f;
    w[m] = wm; sum += wm;
  }
  float inv = 1.f / (sum + 1e-16f);
  #pragma unroll
  for (int m = 0; m < MSUB; ++m) htw[n*MSUB + m] = w[m]*inv;
}

// ---------------- GINE gather, eager-4 edges: out[f] = x[f] + sum relu(x[src]+ea) ----------------

__global__ void k_gine_gather(float* __restrict__ outa, const float* __restrict__ x,
                              const float* __restrict__ ea, const int* __restrict__ cnt,
                              const int2* __restrict__ beid, int rows, int cap){
  int idx = blockIdx.x*256 + threadIdx.x;
  if (idx >= rows*H4) return;
  int f = idx >> 5; int c = (idx & 31) << 2;
  int n = cnt[f]; if (n > cap) n = cap;
  const int2* bl = beid + (size_t)f*cap;
  // eager: issue all 4 edge-record loads in parallel (cap >= 4; poison masked below)
  int2 e0 = bl[0], e1 = bl[1], e2 = bl[2], e3 = bl[3];
  int s0 = (0 < n) ? e0.y : 0, a0 = (0 < n) ? e0.x : 0;
  int s1 = (1 < n) ? e1.y : 0, a1 = (1 < n) ? e1.x : 0;
  int s2 = (2 < n) ? e2.y : 0, a2 = (2 < n) ? e2.x : 0;
  int s3 = (3 < n) ? e3.y : 0, a3 = (3 < n) ? e3.x : 0;
  float4 acc = *(const float4*)(x + (size_t)f*H + c);
  float4 xv0 = *(const float4*)(x + (size_t)s0*H + c);
  float4 ev0 = *(const float4*)(ea + (size_t)a0*H + c);
  float4 xv1 = *(const float4*)(x + (size_t)s1*H + c);
  float4 ev1 = *(const float4*)(ea + (size_t)a1*H + c);
  float4 xv2 = *(const float4*)(x + (size_t)s2*H + c);
  float4 ev2 = *(const float4*)(ea + (size_t)a2*H + c);
  float4 xv3 = *(const float4*)(x + (size_t)s3*H + c);
  float4 ev3 = *(const float4*)(ea + (size_t)a3*H + c);
  if (0 < n){
    acc.x += fmaxf(xv0.x+ev0.x,0.f); acc.y += fmaxf(xv0.y+ev0.y,0.f);
    acc.z += fmaxf(xv0.z+ev0.z,0.f); acc.w += fmaxf(xv0.w+ev0.w,0.f);
  }
  if (1 < n){
    acc.x += fmaxf(xv1.x+ev1.x,0.f); acc.y += fmaxf(xv1.y+ev1.y,0.f);
    acc.z += fmaxf(xv1.z+ev1.z,0.f); acc.w += fmaxf(xv1.w+ev1.w,0.f);
  }
  if (2 < n){
    acc.x += fmaxf(xv2.x+ev2.x,0.f); acc.y += fmaxf(xv2.y+ev2.y,0.f);
    acc.z += fmaxf(xv2.z+ev2.z,0.f); acc.w += fmaxf(xv2.w+ev2.w,0.f);
  }
  if (3 < n){
    acc.x += fmaxf(xv3.x+ev3.x,0.f); acc.y += fmaxf(xv3.y+ev3.y,0.f);
    acc.z += fmaxf(xv3.z+ev3.z,0.f); acc.w += fmaxf(xv3.w+ev3.w,0.f);
  }
  for (int i = 4; i < n; ++i){
    int2 es = bl[i];
    float4 xv = *(const float4*)(x + (size_t)es.y*H + c);
    float4 ev = *(const float4*)(ea + (size_t)es.x*H + c);
    acc.x += fmaxf(xv.x+ev.x,0.f); acc.y += fmaxf(xv.y+ev.y,0.f);
    acc.z += fmaxf(xv.z+ev.z,0.f); acc.w += fmaxf(xv.w+ev.w,0.f);
  }
  *(float4*)(outa + (size_t)f*H + c) = acc;
}

// ---------------- HT root gather to canonical nodes ----------------

__global__ void k_canon(float* __restrict__ canon, const float* __restrict__ h,
                        const float* __restrict__ htw, const int* __restrict__ rfi){
  int idx = blockIdx.x*256 + threadIdx.x;
  if (idx >= NN*H4) return;
  int n = idx >> 5; int c = (idx & 31) << 2;
  float4 acc = make_float4(0.f,0.f,0.f,0.f);
  #pragma unroll
  for (int m = 0; m < MSUB; ++m){
    int s = n*MSUB + m;
    float w = htw[s];
    const float* p = h + (size_t)rfi[s]*H + c;
    acc.x += w*p[0]; acc.y += w*p[1]; acc.z += w*p[2]; acc.w += w*p[3];
  }
  *(float4*)(canon + (size_t)n*H + c) = acc;
}

// ---------------- split-bf16 MFMA matmul, N-split over blockIdx.y ----------------
// Each block: 64 rows x 64 cols (cols [y*64, y*64+64), mapped col = nt*16+n15,
// nt = y*4 + nt4). 32 KB LDS -> 4 blocks/CU (16 waves/CU) for latency hiding.
// mode 0: out = in@W + bias;  mode 1: + relu
// mode 2: fused combine (FF only): r1 = in@W+bias; h1 = bn(hmid)*vf;
//         root: o = h1 + hinter[nid]*vf; else o = h1 + r1 + r2[r/12]; out = relu(o)*vf

__global__ __launch_bounds__(256, 4) void k_mm_mfma(
    const float* __restrict__ in, float* __restrict__ out, int rows,
    const short* __restrict__ wf, const float* __restrict__ bias,
    int mode, const int* __restrict__ gather,
    const float* __restrict__ hmid, const float* __restrict__ r2,
    const float* __restrict__ hinter, const float* __restrict__ muinv,
    const float* __restrict__ bg, const float* __restrict__ bb,
    const int* __restrict__ nids)
{
  __shared__ __align__(16) short wfrag[HALF_SHORTS];   // 32 KB
  int tid = threadIdx.x;
  int y = blockIdx.y;
  {
    const float4* s4 = (const float4*)(wf + (size_t)y*HALF_SHORTS);
    float4* d4 = (float4*)wfrag;
    #pragma unroll
    for (int i = 0; i < 8; ++i) d4[tid + i*256] = s4[tid + i*256];
  }
  __syncthreads();

  int w = tid >> 6, l = tid & 63;
  int quad = l >> 4, n15 = l & 15;

  // hoisted per-lane column constants (4 cols per lane: col = (y*4+t)*16 + n15)
  float bv[4], mu[4], iv[4], gv[4], be[4];
  #pragma unroll
  for (int t = 0; t < 4; ++t){
    int col = (y*4 + t)*16 + n15;
    bv[t] = bias[col];
    if (mode == 2){
      mu[t] = muinv[col]; iv[t] = muinv[H+col];
      gv[t] = bg[col];    be[t] = bb[col];
    }
  }

  int ngroups = (rows + 63) >> 6;
  for (int g = blockIdx.x; g < ngroups; g += gridDim.x){
    int rload = g*64 + w*16 + n15;
    bool ok = rload < rows;
    int ir = ok ? (gather ? gather[rload] : rload) : 0;
    const float* ap = in + (size_t)ir*H + quad*8;

    short8 ah[4], al[4];
    #pragma unroll
    for (int ks = 0; ks < 4; ++ks){
      float4 a0 = ok ? *(const float4*)(ap + ks*32)     : make_float4(0.f,0.f,0.f,0.f);
      float4 a1 = ok ? *(const float4*)(ap + ks*32 + 4) : make_float4(0.f,0.f,0.f,0.f);
      float av[8] = {a0.x,a0.y,a0.z,a0.w,a1.x,a1.y,a1.z,a1.w};
      #pragma unroll
      for (int j = 0; j < 8; ++j){
        unsigned short hb = f2bf_rne(av[j]);
        float hf = __uint_as_float((unsigned)hb << 16);
        ah[ks][j] = (short)hb;
        al[ks][j] = (short)f2bf_rne(av[j] - hf);
      }
    }

    floatx4 acc[4] = {};
    #pragma unroll
    for (int ks = 0; ks < 4; ++ks){
      #pragma unroll
      for (int t = 0; t < 4; ++t){
        short8 bh  = *(const short8*)&wfrag[((ks*4 + t)*64 + l)*8];
        short8 blo = *(const short8*)&wfrag[(((4 + ks)*4 + t)*64 + l)*8];
        acc[t] = __builtin_amdgcn_mfma_f32_16x16x32_bf16(ah[ks], bh,  acc[t], 0, 0, 0);
        acc[t] = __builtin_amdgcn_mfma_f32_16x16x32_bf16(al[ks], bh,  acc[t], 0, 0, 0);
        acc[t] = __builtin_amdgcn_mfma_f32_16x16x32_bf16(ah[ks], blo, acc[t], 0, 0, 0);
      }
    }

    int rbase = g*64 + w*16 + quad*4;
    if (mode != 2){
      #pragma unroll
      for (int t = 0; t < 4; ++t){
        int col = (y*4 + t)*16 + n15;
        #pragma unroll
        for (int reg = 0; reg < 4; ++reg){
          int r = rbase + reg;
          if (r < rows){
            float v = acc[t][reg] + bv[t];
            if (mode == 1) v = fmaxf(v, 0.f);
            out[(size_t)r*H + col] = v;
          }
        }
      }
    } else {
      #pragma unroll
      for (int reg = 0; reg < 4; ++reg){
        int r = rbase + reg;              // FF % 64 == 0: in range
        int nid = nids[r];
        float vf = (nid >= 0) ? 1.f : 0.f;
        int cid = (nid < 0) ? 0 : nid;
        bool isroot = (r % KK) == 0;
        const float* srcp = isroot ? (hinter + (size_t)cid*H) : (r2 + (size_t)(r/KK)*H);
        #pragma unroll
        for (int t = 0; t < 4; ++t){
          int col = (y*4 + t)*16 + n15;
          float h1 = ((hmid[(size_t)r*H + col] - mu[t])*iv[t]*gv[t] + be[t])*vf;
          float o;
          if (isroot) o = h1 + srcp[col]*vf;
          else        o = h1 + (acc[t][reg] + bv[t]) + srcp[col];
          out[(size_t)r*H + col] = fmaxf(o, 0.f)*vf;
        }
      }
    }
  }
}

// ---------------- BatchNorm ----------------

__global__ void k_bnstats(const float* __restrict__ x, int rows, double* __restrict__ stats){
  int g = blockIdx.x*256 + threadIdx.x;
  int c = g & (H-1);
  int rstart = g >> 7;
  int rstride = (gridDim.x*256) >> 7;
  double s = 0.0, s2 = 0.0;
  for (int r = rstart; r < rows; r += rstride){
    float v = x[(size_t)r*H + c];
    s += v; s2 += (double)v*(double)v;
  }
  atomicAdd(&stats[c], s);
  atomicAdd(&stats[H+c], s2);
}

__global__ void k_bnfin(double* __restrict__ stats, int rows, float* __restrict__ muinv){
  int c = threadIdx.x;
  if (c < H){
    double mu = stats[c] / (double)rows;
    double var = stats[H+c] / (double)rows - mu*mu;
    muinv[c]   = (float)mu;
    muinv[H+c] = (float)(1.0 / sqrt(var + (double)BN_EPS));
    stats[c] = 0.0; stats[H+c] = 0.0;
  }
}

__global__ void k_bnapply(float* __restrict__ x, const float* __restrict__ muinv,
                          const float* __restrict__ g, const float* __restrict__ b, int rows){
  int idx = blockIdx.x*256 + threadIdx.x;
  if (idx >= rows*H4) return;
  int r = idx >> 5; int c = (idx & 31) << 2;
  float4 v  = *(const float4*)(x + (size_t)r*H + c);
  float4 mu = *(const float4*)(muinv + c);
  float4 iv = *(const float4*)(muinv + H + c);
  float4 gg = *(const float4*)(g + c);
  float4 bb = *(const float4*)(b + c);
  v.x = (v.x-mu.x)*iv.x*gg.x + bb.x;
  v.y = (v.y-mu.y)*iv.y*gg.y + bb.y;
  v.z = (v.z-mu.z)*iv.z*gg.z + bb.z;
  v.w = (v.w-mu.w)*iv.w*gg.w + bb.w;
  *(float4*)(x + (size_t)r*H + c) = v;
}

// ---------------- readout ----------------

__global__ void k_hsub(float* __restrict__ hsub, const float* __restrict__ h){
  int idx = blockIdx.x*256 + threadIdx.x;
  if (idx >= SS*H4) return;
  int s = idx >> 5; int c = (idx & 31) << 2;
  float4 acc = make_float4(0.f,0.f,0.f,0.f);
  const float* base = h + (size_t)s*KK*H + c;
  #pragma unroll
  for (int k = 0; k < KK; ++k){
    float4 v = *(const float4*)(base + (size_t)k*H);
    acc.x += v.x; acc.y += v.y; acc.z += v.z; acc.w += v.w;
  }
  *(float4*)(hsub + (size_t)s*H + c) = acc;
}

__global__ void k_poolw(float* __restrict__ poolw, const float* __restrict__ lp,
                        const float* __restrict__ alpha){
  int n = blockIdx.x*256 + threadIdx.x;
  if (n >= NN) return;
  float a = alpha[0];
  float s0 = -a*lp[n*MSUB+0], s1 = -a*lp[n*MSUB+1], s2 = -a*lp[n*MSUB+2], s3 = -a*lp[n*MSUB+3];
  float m = fmaxf(fmaxf(s0,s1), fmaxf(s2,s3));
  float e0 = expf(s0-m), e1 = expf(s1-m), e2 = expf(s2-m), e3 = expf(s3-m);
  float sum = e0+e1+e2+e3;
  poolw[n*MSUB+0] = e0/sum; poolw[n*MSUB+1] = e1/sum;
  poolw[n*MSUB+2] = e2/sum; poolw[n*MSUB+3] = e3/sum;
}

__global__ void k_nodeemb(float* __restrict__ nemb, const float* __restrict__ hsub,
                          const float* __restrict__ poolw){
  int idx = blockIdx.x*256 + threadIdx.x;
  if (idx >= NN*H4) return;
  int n = idx >> 5; int c = (idx & 31) << 2;
  float w0 = poolw[n*MSUB+0], w1 = poolw[n*MSUB+1], w2 = poolw[n*MSUB+2], w3 = poolw[n*MSUB+3];
  const float* base = hsub + (size_t)n*MSUB*H + c;
  float4 v0 = *(const float4*)(base + 0*H);
  float4 v1 = *(const float4*)(base + 1*H);
  float4 v2 = *(const float4*)(base + 2*H);
  float4 v3 = *(const float4*)(base + 3*H);
  float4 o;
  o.x = w0*v0.x + w1*v1.x + w2*v2.x + w3*v3.x;
  o.y = w0*v0.y + w1*v1.y + w2*v2.y + w3*v3.y;
  o.z = w0*v0.z + w1*v1.z + w2*v2.z + w3*v3.z;
  o.w = w0*v0.w + w1*v1.w + w2*v2.w + w3*v3.w;
  *(float4*)(nemb + (size_t)n*H + c) = o;
}

__global__ void k_out(float* __restrict__ out, const float* __restrict__ nemb,
                      const float* __restrict__ muinv, const float* __restrict__ g,
                      const float* __restrict__ b){
  int idx = blockIdx.x*256 + threadIdx.x;
  if (idx >= NBATCH*H) return;
  int bi = idx >> 7; int c = idx & (H-1);
  float mu = muinv[c], iv = muinv[H+c], gg = g[c], bb = b[c];
  float acc = 0.f;
  const float* base = nemb + (size_t)bi*(NN/NBATCH)*H + c;
  for (int i = 0; i < NN/NBATCH; ++i)
    acc += (base[(size_t)i*H] - mu)*iv*gg + bb;
  out[idx] = acc;
}

// ---------------- launch ----------------

extern "C" void kernel_launch(void* const* d_in, const int* in_sizes, int n_in,
                              void* d_out, int out_size, void* d_ws, size_t ws_size,
                              hipStream_t stream) {
  const int*   x_tok      = (const int*)  d_in[0];
  const int*   dist       = (const int*)  d_in[1];
  const int*   node_ids   = (const int*)  d_in[2];
  const int*   sub_batch  = (const int*)  d_in[4];
  const int*   rfi        = (const int*)  d_in[5];
  const int*   intra_ei   = (const int*)  d_in[6];
  const int*   edge_index = (const int*)  d_in[7];
  const float* lp         = (const float*)d_in[9];
  const float* ea_flat    = (const float*)d_in[10];
  const float* edge_attr  = (const float*)d_in[11];
  const float* atom_emb   = (const float*)d_in[12];
  const float* dist_emb   = (const float*)d_in[13];
  const float* logp_w     = (const float*)d_in[14];
  const float* logp_b     = (const float*)d_in[15];
  const float* intra_W1   = (const float*)d_in[16];
  const float* intra_b1   = (const float*)d_in[17];
  const float* intra_W2   = (const float*)d_in[18];
  const float* intra_b2   = (const float*)d_in[19];
  const float* intra_bn_g = (const float*)d_in[20];
  const float* intra_bn_b = (const float*)d_in[21];
  const float* self_W     = (const float*)d_in[22];
  const float* self_b     = (const float*)d_in[23];
  const float* root_W     = (const float*)d_in[24];
  const float* root_b     = (const float*)d_in[25];
  const float* inter_W1   = (const float*)d_in[26];
  const float* inter_b1   = (const float*)d_in[27];
  const float* inter_W2   = (const float*)d_in[28];
  const float* inter_b2   = (const float*)d_in[29];
  const float* inter_bn_g = (const float*)d_in[30];
  const float* inter_bn_b = (const float*)d_in[31];
  const float* ro_bn_g    = (const float*)d_in[32];
  const float* ro_bn_b    = (const float*)d_in[33];
  const float* alpha_pool = (const float*)d_in[34];
  const float* alpha_inter= (const float*)d_in[35];

  const int* isrc = intra_ei;
  const int* idst = intra_ei + EINTRA;
  const int* esrc = edge_index;
  const int* edst = edge_index + EINTER;

  float* out = (float*)d_out;

  char* ws = (char*)d_ws;
  size_t off = 0;
  auto nxt = [&](size_t bytes) -> void* {
    void* p = ws + off;
    off += (bytes + 255) & ~(size_t)255;
    return p;
  };
  float*  hA     = (float*) nxt((size_t)FF*H*4);
  float*  hB     = (float*) nxt((size_t)FF*H*4);
  float*  hmid   = (float*) nxt((size_t)FF*H*4);
  float*  tbuf   = (float*) nxt((size_t)FF*H*4);
  float*  r2     = (float*) nxt((size_t)SS*H*4);
  float*  canon  = (float*) nxt((size_t)NN*H*4);
  float*  agg2   = (float*) nxt((size_t)NN*H*4);
  float*  hsub   = (float*) nxt((size_t)SS*H*4);
  float*  nemb   = (float*) nxt((size_t)NN*H*4);
  float*  htw    = (float*) nxt((size_t)SS*4);
  float*  poolw  = (float*) nxt((size_t)NN*MSUB*4);
  double* statsA = (double*)nxt((size_t)2*H*8);
  double* statsB = (double*)nxt((size_t)2*H*8);
  float*  muinvA = (float*) nxt((size_t)2*H*4);
  float*  muinvB = (float*) nxt((size_t)2*H*4);
  short*  wsplit = (short*) nxt((size_t)24*WFRAG_SHORTS*2);
  int*    icnt   = (int*)   nxt((size_t)FF*4);
  int2*   ibeid  = (int2*)  nxt((size_t)FF*CAP_I*8);
  int*    ecnt   = (int*)   nxt((size_t)NN*4);
  int2*   ebeid  = (int2*)  nxt((size_t)NN*CAP_E*8);
  (void)ws_size; (void)n_in; (void)in_sizes; (void)out_size; (void)sub_batch;

  const int G_FH4 = FF*H4/256;
  const int G_SH4 = SS*H4/256;
  const int G_NH4 = (NN*H4 + 255)/256;
  const int G_N   = (NN + 255)/256;
  const dim3 G_MM_F(512, 2);                 // 1024 blocks, 4/CU
  const dim3 G_MM_S((SS + 63)/64, 2);
  const dim3 G_MM_N((NN + 63)/64, 2);

  k_zero<<<2, 256, 0, stream>>>((float*)statsA, 2*H*2);
  k_zero<<<2, 256, 0, stream>>>((float*)statsB, 2*H*2);
  k_zeroi<<<(FF+255)/256, 256, 0, stream>>>(icnt, FF);
  k_zeroi<<<G_N, 256, 0, stream>>>(ecnt, NN);

  k_wprep<<<dim3(16,24), 256, 0, stream>>>(intra_W1, intra_W2, self_W, root_W,
                                           inter_W1, inter_W2, wsplit);
  k_bucket2<<<(EINTRA+255)/256, 256, 0, stream>>>(idst, isrc, EINTRA, icnt, ibeid, CAP_I);
  k_bucket2<<<(EINTER+255)/256, 256, 0, stream>>>(edst, esrc, EINTER, ecnt, ebeid, CAP_E);

  k_encode<<<G_FH4, 256, 0, stream>>>(hA, x_tok, dist, node_ids, sub_batch, lp,
                                      atom_emb, dist_emb, logp_w, logp_b);
  k_htw<<<G_N, 256, 0, stream>>>(node_ids, rfi, lp, alpha_inter, htw);

  float* hcur = hA;
  float* hnxt = hB;
  for (int l = 0; l < NLAYER; ++l){
    const short* wfL = wsplit + (size_t)l*6*WFRAG_SHORTS;

    // intra GINE stage1 as gather
    k_gine_gather<<<G_FH4, 256, 0, stream>>>(hmid, hcur, ea_flat, icnt, ibeid, FF, CAP_I);
    // intra MLP
    k_mm_mfma<<<G_MM_F, 256, 0, stream>>>(hmid, tbuf, FF, wfL + 0*WFRAG_SHORTS,
        intra_b1 + (size_t)l*H, 1, nullptr,
        nullptr,nullptr,nullptr,nullptr,nullptr,nullptr,nullptr);
    k_mm_mfma<<<G_MM_F, 256, 0, stream>>>(tbuf, hmid, FF, wfL + 1*WFRAG_SHORTS,
        intra_b2 + (size_t)l*H, 0, nullptr,
        nullptr,nullptr,nullptr,nullptr,nullptr,nullptr,nullptr);
    k_bnstats<<<512, 256, 0, stream>>>(hmid, FF, statsA);
    k_bnfin<<<1, 128, 0, stream>>>(statsA, FF, muinvA);

    // HT root gather + r2
    k_canon<<<G_NH4, 256, 0, stream>>>(canon, hcur, htw, rfi);
    k_mm_mfma<<<G_MM_S, 256, 0, stream>>>(hcur, r2, SS, wfL + 3*WFRAG_SHORTS,
        root_b + (size_t)l*H, 0, rfi,
        nullptr,nullptr,nullptr,nullptr,nullptr,nullptr,nullptr);

    // inter GINE
    k_gine_gather<<<G_NH4, 256, 0, stream>>>(agg2, canon, edge_attr, ecnt, ebeid, NN, CAP_E);
    k_mm_mfma<<<G_MM_N, 256, 0, stream>>>(agg2, tbuf, NN, wfL + 4*WFRAG_SHORTS,
        inter_b1 + (size_t)l*H, 1, nullptr,
        nullptr,nullptr,nullptr,nullptr,nullptr,nullptr,nullptr);
    k_mm_mfma<<<G_MM_N, 256, 0, stream>>>(tbuf, agg2, NN, wfL + 5*WFRAG_SHORTS,
        inter_b2 + (size_t)l*H, 0, nullptr,
        nullptr,nullptr,nullptr,nullptr,nullptr,nullptr,nullptr);
    k_bnstats<<<128, 256, 0, stream>>>(agg2, NN, statsB);
    k_bnfin<<<1, 128, 0, stream>>>(statsB, NN, muinvB);
    k_bnapply<<<G_NH4, 256, 0, stream>>>(agg2, muinvB, inter_bn_g + (size_t)l*H,
                                         inter_bn_b + (size_t)l*H, NN);

    // fused self-matmul + combine -> hnxt (ping-pong, no aliasing)
    k_mm_mfma<<<G_MM_F, 256, 0, stream>>>(hcur, hnxt, FF, wfL + 2*WFRAG_SHORTS,
        self_b + (size_t)l*H, 2, nullptr,
        hmid, r2, agg2, muinvA,
        intra_bn_g + (size_t)l*H, intra_bn_b + (size_t)l*H, node_ids);

    float* t = hcur; hcur = hnxt; hnxt = t;
  }

  // readout
  k_hsub<<<G_SH4, 256, 0, stream>>>(hsub, hcur);
  k_poolw<<<G_N, 256, 0, stream>>>(poolw, lp, alpha_pool);
  k_nodeemb<<<G_NH4, 256, 0, stream>>>(nemb, hsub, poolw);
  k_bnstats<<<128, 256, 0, stream>>>(nemb, NN, statsB);
  k_bnfin<<<1, 128, 0, stream>>>(statsB, NN, muinvB);
  k_out<<<(NBATCH*H+255)/256, 256, 0, stream>>>(out, nemb, muinvB, ro_bn_g, ro_bn_b);
}